// Round 1
// baseline (1820.576 us; speedup 1.0000x reference)
//
#include <hip/hip_runtime.h>
#include <hip/hip_bf16.h>

#define NNODES 50000
#define MLP_HID 200

__device__ __forceinline__ unsigned enc_f(float v){
    unsigned u = __float_as_uint(v);
    return (u & 0x80000000u) ? ~u : (u | 0x80000000u);
}
__device__ __forceinline__ float dec_f(unsigned e){
    return __uint_as_float((e & 0x80000000u) ? (e ^ 0x80000000u) : ~e);
}

// ---------------- GEMM: C[M x Nc] = A[M x KT] @ B[KT x Nc] (+bias, +relu) ----
template<int KT, bool RELU>
__global__ __launch_bounds__(256) void gemm_tile(const float* __restrict__ A,
                                                 const float* __restrict__ B,
                                                 const float* __restrict__ bias,
                                                 float* __restrict__ C,
                                                 int M, int Nc){
    __shared__ float As[16][64];
    __shared__ float Bs[16][64];
    const int tid = threadIdx.x;
    const int tx = tid & 15, ty = tid >> 4;
    const int r0 = blockIdx.y * 64, c0 = blockIdx.x * 64;
    float acc[4][4] = {};
    const int lr  = tid >> 2,  lk4 = (tid & 3) * 4;   // A-tile load map
    const int bk  = tid >> 4,  bc4 = (tid & 15) * 4;  // B-tile load map

    for (int k0 = 0; k0 < KT; k0 += 16){
        float4 av = make_float4(0.f,0.f,0.f,0.f);
        if (r0 + lr < M) av = *(const float4*)&A[(size_t)(r0 + lr) * KT + k0 + lk4];
        As[lk4+0][lr] = av.x; As[lk4+1][lr] = av.y;
        As[lk4+2][lr] = av.z; As[lk4+3][lr] = av.w;

        if (c0 + bc4 + 3 < Nc){
            float4 bv = *(const float4*)&B[(size_t)(k0 + bk) * Nc + c0 + bc4];
            Bs[bk][bc4+0] = bv.x; Bs[bk][bc4+1] = bv.y;
            Bs[bk][bc4+2] = bv.z; Bs[bk][bc4+3] = bv.w;
        } else {
            #pragma unroll
            for (int j = 0; j < 4; j++){
                int c = c0 + bc4 + j;
                Bs[bk][bc4+j] = (c < Nc) ? B[(size_t)(k0 + bk) * Nc + c] : 0.f;
            }
        }
        __syncthreads();
        #pragma unroll
        for (int kk = 0; kk < 16; kk++){
            float4 a = *(const float4*)&As[kk][ty*4];
            float4 b = *(const float4*)&Bs[kk][tx*4];
            float ar[4] = {a.x,a.y,a.z,a.w};
            float br[4] = {b.x,b.y,b.z,b.w};
            #pragma unroll
            for (int i = 0; i < 4; i++)
                #pragma unroll
                for (int j = 0; j < 4; j++)
                    acc[i][j] = fmaf(ar[i], br[j], acc[i][j]);
        }
        __syncthreads();
    }
    #pragma unroll
    for (int i = 0; i < 4; i++){
        int r = r0 + ty*4 + i;
        if (r >= M) continue;
        #pragma unroll
        for (int j = 0; j < 4; j++){
            int c = c0 + tx*4 + j;
            if (c >= Nc) continue;
            float v = acc[i][j];
            if (bias) v += bias[c];
            if (RELU) v = fmaxf(v, 0.f);
            C[(size_t)r * Nc + c] = v;
        }
    }
}

// ---------------- el/er: per (n,h) dot(h[n,h,:], al[h,:]) -------------------
__global__ __launch_bounds__(256) void attn_dots(const float* __restrict__ h,
                                                 const float* __restrict__ al,
                                                 const float* __restrict__ ar,
                                                 float* __restrict__ el,
                                                 float* __restrict__ er,
                                                 int n_total /* N*H */){
    int g = blockIdx.x * blockDim.x + threadIdx.x;
    int idx = g >> 6;
    if (idx >= n_total) return;
    int lane = threadIdx.x & 63;
    int hh = idx & 3;
    float v  = h[(size_t)idx * 64 + lane];
    float vl = v * al[hh * 64 + lane];
    float vr = v * ar[hh * 64 + lane];
    #pragma unroll
    for (int o = 32; o > 0; o >>= 1){
        vl += __shfl_xor(vl, o);
        vr += __shfl_xor(vr, o);
    }
    if (lane == 0){ el[idx] = vl; er[idx] = vr; }
}

// ---------------- edge pass 1: e = leaky_relu(el[src]+er[dst]); max over dst -
__global__ __launch_bounds__(256) void edge_pass1(const float* __restrict__ el,
                                                  const float* __restrict__ er,
                                                  const int* __restrict__ src,
                                                  const int* __restrict__ dst,
                                                  float* __restrict__ e_buf,
                                                  unsigned* __restrict__ m_enc,
                                                  int E){
    int t = blockIdx.x * blockDim.x + threadIdx.x;
    if (t >= E * 4) return;
    int e = t >> 2, hh = t & 3;
    int sN = src[e], dN = dst[e];
    float v = el[sN * 4 + hh] + er[dN * 4 + hh];
    v = (v >= 0.f) ? v : 0.2f * v;
    e_buf[t] = v;
    atomicMax(&m_enc[dN * 4 + hh], enc_f(v));
}

// ---------------- edge pass 2: ex = exp(e - m[dst]); sum over dst ------------
__global__ __launch_bounds__(256) void edge_pass2(const int* __restrict__ dst,
                                                  float* __restrict__ e_buf,
                                                  const unsigned* __restrict__ m_enc,
                                                  float* __restrict__ s_sum,
                                                  int E){
    int t = blockIdx.x * blockDim.x + threadIdx.x;
    if (t >= E * 4) return;
    int e = t >> 2, hh = t & 3;
    int dN = dst[e];
    float m = dec_f(m_enc[dN * 4 + hh]);
    float ex = expf(e_buf[t] - m);
    e_buf[t] = ex;
    atomicAdd(&s_sum[dN * 4 + hh], ex);
}

// ---------------- edge pass 3: normalize a = ex / s[dst] ---------------------
__global__ __launch_bounds__(256) void edge_norm(const int* __restrict__ dst,
                                                 float* __restrict__ e_buf,
                                                 const float* __restrict__ s_sum,
                                                 int E){
    int t = blockIdx.x * blockDim.x + threadIdx.x;
    if (t >= E * 4) return;
    int e = t >> 2, hh = t & 3;
    e_buf[t] = e_buf[t] / s_sum[dst[e] * 4 + hh];
}

// ---------------- edge aggregation: agg[dst] += a * h[src] -------------------
__global__ __launch_bounds__(256) void edge_agg(const int* __restrict__ src,
                                                const int* __restrict__ dst,
                                                const float* __restrict__ e_buf,
                                                const float* __restrict__ hfeat,
                                                float* __restrict__ agg,
                                                int E){
    int t = blockIdx.x * blockDim.x + threadIdx.x;
    int e = t >> 6;
    if (e >= E) return;
    int d = t & 63;
    int sN = src[e], dN = dst[e];
    #pragma unroll
    for (int hh = 0; hh < 4; hh++){
        float w = e_buf[e * 4 + hh];
        atomicAdd(&agg[(size_t)dN * 256 + hh * 64 + d],
                  w * hfeat[(size_t)sN * 256 + hh * 64 + d]);
    }
}

// ---------------- node epilogue: mean_h relu(agg + b) ------------------------
__global__ __launch_bounds__(256) void node_ep(const float* __restrict__ agg,
                                               const float* __restrict__ b,
                                               float* __restrict__ out){
    int t = blockIdx.x * blockDim.x + threadIdx.x;
    if (t >= NNODES * 64) return;
    int n = t >> 6, d = t & 63;
    float acc = 0.f;
    #pragma unroll
    for (int hh = 0; hh < 4; hh++){
        float v = agg[(size_t)n * 256 + hh * 64 + d] + b[hh * 64 + d];
        acc += fmaxf(v, 0.f);
    }
    out[t] = acc * 0.25f;
}

// ---------------- BN stats: per-column sum & sumsq ---------------------------
__global__ __launch_bounds__(256) void bn_stats(const float* __restrict__ z,
                                                float* __restrict__ bsum,
                                                float* __restrict__ bsumsq,
                                                int Nrows){
    int col = threadIdx.x;
    if (col >= MLP_HID) return;
    int r0 = blockIdx.x * 256;
    int r1 = min(r0 + 256, Nrows);
    float s = 0.f, ss = 0.f;
    for (int r = r0; r < r1; r++){
        float v = z[(size_t)r * MLP_HID + col];
        s += v; ss += v * v;
    }
    atomicAdd(&bsum[col], s);
    atomicAdd(&bsumsq[col], ss);
}

__global__ void bn_final(const float* __restrict__ bsum,
                         const float* __restrict__ bsumsq,
                         const float* __restrict__ gamma,
                         const float* __restrict__ beta,
                         float* __restrict__ scale,
                         float* __restrict__ shift,
                         int Nrows){
    int col = threadIdx.x;
    if (col >= MLP_HID) return;
    float inv = 1.f / (float)Nrows;
    float mu = bsum[col] * inv;
    float var = bsumsq[col] * inv - mu * mu;
    float rstd = rsqrtf(var + 1e-5f);
    float sc = rstd * gamma[col];
    scale[col] = sc;
    shift[col] = beta[col] - mu * sc;
}

// ---------------- final: out = bn(z) @ Wm2 + bm2, one wave per node ----------
__global__ __launch_bounds__(256) void mlp2(const float* __restrict__ z,
                                            const float* __restrict__ scale,
                                            const float* __restrict__ shift,
                                            const float* __restrict__ Wm2,
                                            const float* __restrict__ bm2,
                                            float* __restrict__ out,
                                            int Nrows){
    int g = blockIdx.x * blockDim.x + threadIdx.x;
    int n = g >> 6;
    if (n >= Nrows) return;
    int lane = threadIdx.x & 63;
    float a0 = 0.f, a1 = 0.f;
    for (int k = lane; k < MLP_HID; k += 64){
        float zn = z[(size_t)n * MLP_HID + k] * scale[k] + shift[k];
        a0 = fmaf(zn, Wm2[k * 2 + 0], a0);
        a1 = fmaf(zn, Wm2[k * 2 + 1], a1);
    }
    #pragma unroll
    for (int o = 32; o > 0; o >>= 1){
        a0 += __shfl_xor(a0, o);
        a1 += __shfl_xor(a1, o);
    }
    if (lane == 0){
        out[n * 2 + 0] = a0 + bm2[0];
        out[n * 2 + 1] = a1 + bm2[1];
    }
}

extern "C" void kernel_launch(void* const* d_in, const int* in_sizes, int n_in,
                              void* d_out, int out_size, void* d_ws, size_t ws_size,
                              hipStream_t stream) {
    const float* feat  = (const float*)d_in[0];
    const int*   src   = (const int*)  d_in[1];
    const int*   dst   = (const int*)  d_in[2];
    const float* W1    = (const float*)d_in[3];
    const float* al1   = (const float*)d_in[4];
    const float* ar1   = (const float*)d_in[5];
    const float* b1    = (const float*)d_in[6];
    const float* W2    = (const float*)d_in[7];
    const float* al2   = (const float*)d_in[8];
    const float* ar2   = (const float*)d_in[9];
    const float* b2    = (const float*)d_in[10];
    const float* Wm1   = (const float*)d_in[11];
    const float* bm1   = (const float*)d_in[12];
    const float* gamma = (const float*)d_in[13];
    const float* beta  = (const float*)d_in[14];
    const float* Wm2   = (const float*)d_in[15];
    const float* bm2   = (const float*)d_in[16];
    const int E = in_sizes[1];
    float* out = (float*)d_out;

    // workspace layout
    float* h_big  = (float*)d_ws;                     // N*256 (h1/h2, then z N*200)
    float* agg    = h_big + (size_t)NNODES * 256;     // N*256
    float* e_buf  = agg   + (size_t)NNODES * 256;     // E*4
    float* out_l  = e_buf + (size_t)E * 4;            // N*64
    float* el     = out_l + (size_t)NNODES * 64;      // N*4
    float* er     = el    + (size_t)NNODES * 4;       // N*4
    unsigned* m_enc = (unsigned*)(er + (size_t)NNODES * 4); // N*4
    float* s_sum  = (float*)(m_enc + (size_t)NNODES * 4);   // N*4
    float* bn_sum   = s_sum  + (size_t)NNODES * 4;    // 200
    float* bn_sumsq = bn_sum + MLP_HID;               // 200
    float* bn_scale = bn_sumsq + MLP_HID;             // 200
    float* bn_shift = bn_scale + MLP_HID;             // 200

    const dim3 blk(256);
    const int eg4  = (E * 4 + 255) / 256;
    const int eg64 = (int)(((size_t)E * 64 + 255) / 256);

    auto run_layer = [&](const float* x, int K, const float* W,
                         const float* al, const float* ar, const float* b){
        hipMemsetAsync(agg, 0, (size_t)NNODES * 256 * 4, stream);
        hipMemsetAsync(m_enc, 0, (size_t)NNODES * 4 * 4 * 2, stream); // m_enc + s_sum
        if (K == 128)
            gemm_tile<128,false><<<dim3(4, (NNODES + 63) / 64), blk, 0, stream>>>(
                x, W, nullptr, h_big, NNODES, 256);
        else
            gemm_tile<64,false><<<dim3(4, (NNODES + 63) / 64), blk, 0, stream>>>(
                x, W, nullptr, h_big, NNODES, 256);
        attn_dots<<<(NNODES * 4 * 64 + 255) / 256, blk, 0, stream>>>(
            h_big, al, ar, el, er, NNODES * 4);
        edge_pass1<<<eg4, blk, 0, stream>>>(el, er, src, dst, e_buf, m_enc, E);
        edge_pass2<<<eg4, blk, 0, stream>>>(dst, e_buf, m_enc, s_sum, E);
        edge_norm <<<eg4, blk, 0, stream>>>(dst, e_buf, s_sum, E);
        edge_agg  <<<eg64, blk, 0, stream>>>(src, dst, e_buf, h_big, agg, E);
        node_ep   <<<(NNODES * 64 + 255) / 256, blk, 0, stream>>>(agg, b, out_l);
    };

    run_layer(feat,  128, W1, al1, ar1, b1);
    run_layer(out_l,  64, W2, al2, ar2, b2);

    // MLP: z = relu(out_l @ Wm1 + bm1)
    gemm_tile<64,true><<<dim3((MLP_HID + 63) / 64, (NNODES + 63) / 64), blk, 0, stream>>>(
        out_l, Wm1, bm1, h_big, NNODES, MLP_HID);

    hipMemsetAsync(bn_sum, 0, 2 * MLP_HID * 4, stream);
    bn_stats<<<(NNODES + 255) / 256, blk, 0, stream>>>(h_big, bn_sum, bn_sumsq, NNODES);
    bn_final<<<1, 256, 0, stream>>>(bn_sum, bn_sumsq, gamma, beta, bn_scale, bn_shift, NNODES);
    mlp2<<<(NNODES * 64 + 255) / 256, blk, 0, stream>>>(
        h_big, bn_scale, bn_shift, Wm2, bm2, out, NNODES);
}

// Round 2
// 939.477 us; speedup vs baseline: 1.9379x; 1.9379x over previous
//
#include <hip/hip_runtime.h>
#include <hip/hip_bf16.h>

#define NNODES 50000
#define MLP_HID 200

// ---------------- GEMM: C[M x Nc] = A[M x KT] @ B[KT x Nc] (+bias, +relu) ----
template<int KT, bool RELU>
__global__ __launch_bounds__(256) void gemm_tile(const float* __restrict__ A,
                                                 const float* __restrict__ B,
                                                 const float* __restrict__ bias,
                                                 float* __restrict__ C,
                                                 int M, int Nc){
    __shared__ float As[16][64];
    __shared__ float Bs[16][64];
    const int tid = threadIdx.x;
    const int tx = tid & 15, ty = tid >> 4;
    const int r0 = blockIdx.y * 64, c0 = blockIdx.x * 64;
    float acc[4][4] = {};
    const int lr  = tid >> 2,  lk4 = (tid & 3) * 4;   // A-tile load map
    const int bk  = tid >> 4,  bc4 = (tid & 15) * 4;  // B-tile load map

    for (int k0 = 0; k0 < KT; k0 += 16){
        float4 av = make_float4(0.f,0.f,0.f,0.f);
        if (r0 + lr < M) av = *(const float4*)&A[(size_t)(r0 + lr) * KT + k0 + lk4];
        As[lk4+0][lr] = av.x; As[lk4+1][lr] = av.y;
        As[lk4+2][lr] = av.z; As[lk4+3][lr] = av.w;

        if (c0 + bc4 + 3 < Nc){
            float4 bv = *(const float4*)&B[(size_t)(k0 + bk) * Nc + c0 + bc4];
            Bs[bk][bc4+0] = bv.x; Bs[bk][bc4+1] = bv.y;
            Bs[bk][bc4+2] = bv.z; Bs[bk][bc4+3] = bv.w;
        } else {
            #pragma unroll
            for (int j = 0; j < 4; j++){
                int c = c0 + bc4 + j;
                Bs[bk][bc4+j] = (c < Nc) ? B[(size_t)(k0 + bk) * Nc + c] : 0.f;
            }
        }
        __syncthreads();
        #pragma unroll
        for (int kk = 0; kk < 16; kk++){
            float4 a = *(const float4*)&As[kk][ty*4];
            float4 b = *(const float4*)&Bs[kk][tx*4];
            float ar[4] = {a.x,a.y,a.z,a.w};
            float br[4] = {b.x,b.y,b.z,b.w};
            #pragma unroll
            for (int i = 0; i < 4; i++)
                #pragma unroll
                for (int j = 0; j < 4; j++)
                    acc[i][j] = fmaf(ar[i], br[j], acc[i][j]);
        }
        __syncthreads();
    }
    #pragma unroll
    for (int i = 0; i < 4; i++){
        int r = r0 + ty*4 + i;
        if (r >= M) continue;
        #pragma unroll
        for (int j = 0; j < 4; j++){
            int c = c0 + tx*4 + j;
            if (c >= Nc) continue;
            float v = acc[i][j];
            if (bias) v += bias[c];
            if (RELU) v = fmaxf(v, 0.f);
            C[(size_t)r * Nc + c] = v;
        }
    }
}

// ---------------- el/er: per (n,h) dot(h[n,h,:], a{l,r}[h,:]) ----------------
__global__ __launch_bounds__(256) void attn_dots(const float* __restrict__ h,
                                                 const float* __restrict__ al,
                                                 const float* __restrict__ ar,
                                                 float* __restrict__ el,
                                                 float* __restrict__ er,
                                                 int n_total /* N*H */){
    int g = blockIdx.x * blockDim.x + threadIdx.x;
    int idx = g >> 6;
    if (idx >= n_total) return;
    int lane = threadIdx.x & 63;
    int hh = idx & 3;
    float v  = h[(size_t)idx * 64 + lane];
    float vl = v * al[hh * 64 + lane];
    float vr = v * ar[hh * 64 + lane];
    #pragma unroll
    for (int o = 32; o > 0; o >>= 1){
        vl += __shfl_xor(vl, o);
        vr += __shfl_xor(vr, o);
    }
    if (lane == 0){ el[idx] = vl; er[idx] = vr; }
}

// ---------------- CSR build ----------------
__global__ __launch_bounds__(256) void csr_count(const int* __restrict__ dst,
                                                 int* __restrict__ cnt, int E){
    int e = blockIdx.x * blockDim.x + threadIdx.x;
    if (e < E) atomicAdd(&cnt[dst[e]], 1);
}

__global__ __launch_bounds__(1024) void csr_scan(const int* __restrict__ cnt,
                                                 int* __restrict__ row_ptr,
                                                 int* __restrict__ cursor){
    __shared__ int part[1024];
    const int t = threadIdx.x;
    const int CH = (NNODES + 1023) / 1024;  // 49
    const int base = t * CH;
    int s = 0;
    for (int i = 0; i < CH; i++){
        int idx = base + i;
        if (idx < NNODES) s += cnt[idx];
    }
    part[t] = s;
    __syncthreads();
    for (int off = 1; off < 1024; off <<= 1){
        int v = (t >= off) ? part[t - off] : 0;
        __syncthreads();
        part[t] += v;
        __syncthreads();
    }
    int run = part[t] - s;   // exclusive prefix of this chunk
    for (int i = 0; i < CH; i++){
        int idx = base + i;
        if (idx < NNODES){
            row_ptr[idx] = run;
            cursor[idx]  = run;
            run += cnt[idx];
        }
    }
    if (t == 1023) row_ptr[NNODES] = part[1023];
}

__global__ __launch_bounds__(256) void csr_scatter(const int* __restrict__ src,
                                                   const int* __restrict__ dst,
                                                   int* __restrict__ cursor,
                                                   int* __restrict__ col_src, int E){
    int e = blockIdx.x * blockDim.x + threadIdx.x;
    if (e >= E) return;
    int pos = atomicAdd(&cursor[dst[e]], 1);
    col_src[pos] = src[e];
}

// ---------------- fused edge softmax + aggregation + epilogue ----------------
// one block per dst node; wave h handles head h; lane = output dim
__global__ __launch_bounds__(256) void gat_edge_fused(
    const int* __restrict__ row_ptr, const int* __restrict__ col_src,
    const float* __restrict__ el, const float* __restrict__ er,
    const float* __restrict__ hfeat, const float* __restrict__ b,
    float* __restrict__ out)
{
    const int n    = blockIdx.x;
    const int lane = threadIdx.x & 63;
    const int h    = threadIdx.x >> 6;
    const int rs = row_ptr[n], re = row_ptr[n + 1];
    const int K  = re - rs;
    const float er_h = er[n * 4 + h];

    // phase 1a: max over edges
    float lm = -1e30f;
    for (int k = lane; k < K; k += 64){
        int s = col_src[rs + k];
        float e = el[s * 4 + h] + er_h;
        e = (e >= 0.f) ? e : 0.2f * e;
        lm = fmaxf(lm, e);
    }
    #pragma unroll
    for (int o = 32; o > 0; o >>= 1) lm = fmaxf(lm, __shfl_xor(lm, o));

    // phase 1b: sum of exp
    float ls = 0.f;
    for (int k = lane; k < K; k += 64){
        int s = col_src[rs + k];
        float e = el[s * 4 + h] + er_h;
        e = (e >= 0.f) ? e : 0.2f * e;
        ls += __expf(e - lm);
    }
    #pragma unroll
    for (int o = 32; o > 0; o >>= 1) ls += __shfl_xor(ls, o);
    const float inv_s = 1.f / ls;

    // phase 2: weighted gather-accumulate
    float acc = 0.f;
    for (int kc = 0; kc < K; kc += 64){
        int rem = min(64, K - kc);
        float w = 0.f; int sidx = 0;
        if (lane < rem){
            int s = col_src[rs + kc + lane];
            float e = el[s * 4 + h] + er_h;
            e = (e >= 0.f) ? e : 0.2f * e;
            w = __expf(e - lm) * inv_s;
            sidx = s;
        }
        for (int j = 0; j < rem; j++){
            float wj = __shfl(w, j);
            int   sj = __shfl(sidx, j);
            acc = fmaf(wj, hfeat[(size_t)sj * 256 + h * 64 + lane], acc);
        }
    }

    // epilogue: relu(acc + b), mean over heads
    float v = fmaxf(acc + b[h * 64 + lane], 0.f);
    __shared__ float red[4][64];
    red[h][lane] = v;
    __syncthreads();
    if (h == 0){
        out[(size_t)n * 64 + lane] =
            (red[0][lane] + red[1][lane] + red[2][lane] + red[3][lane]) * 0.25f;
    }
}

// ---------------- BN stats: per-column sum & sumsq ---------------------------
__global__ __launch_bounds__(256) void bn_stats(const float* __restrict__ z,
                                                float* __restrict__ bsum,
                                                float* __restrict__ bsumsq,
                                                int Nrows){
    int col = threadIdx.x;
    if (col >= MLP_HID) return;
    int r0 = blockIdx.x * 256;
    int r1 = min(r0 + 256, Nrows);
    float s = 0.f, ss = 0.f;
    for (int r = r0; r < r1; r++){
        float v = z[(size_t)r * MLP_HID + col];
        s += v; ss += v * v;
    }
    atomicAdd(&bsum[col], s);
    atomicAdd(&bsumsq[col], ss);
}

__global__ void bn_final(const float* __restrict__ bsum,
                         const float* __restrict__ bsumsq,
                         const float* __restrict__ gamma,
                         const float* __restrict__ beta,
                         float* __restrict__ scale,
                         float* __restrict__ shift,
                         int Nrows){
    int col = threadIdx.x;
    if (col >= MLP_HID) return;
    float inv = 1.f / (float)Nrows;
    float mu = bsum[col] * inv;
    float var = bsumsq[col] * inv - mu * mu;
    float rstd = rsqrtf(var + 1e-5f);
    float sc = rstd * gamma[col];
    scale[col] = sc;
    shift[col] = beta[col] - mu * sc;
}

// ---------------- final: out = bn(z) @ Wm2 + bm2, one wave per node ----------
__global__ __launch_bounds__(256) void mlp2(const float* __restrict__ z,
                                            const float* __restrict__ scale,
                                            const float* __restrict__ shift,
                                            const float* __restrict__ Wm2,
                                            const float* __restrict__ bm2,
                                            float* __restrict__ out,
                                            int Nrows){
    int g = blockIdx.x * blockDim.x + threadIdx.x;
    int n = g >> 6;
    if (n >= Nrows) return;
    int lane = threadIdx.x & 63;
    float a0 = 0.f, a1 = 0.f;
    for (int k = lane; k < MLP_HID; k += 64){
        float zn = z[(size_t)n * MLP_HID + k] * scale[k] + shift[k];
        a0 = fmaf(zn, Wm2[k * 2 + 0], a0);
        a1 = fmaf(zn, Wm2[k * 2 + 1], a1);
    }
    #pragma unroll
    for (int o = 32; o > 0; o >>= 1){
        a0 += __shfl_xor(a0, o);
        a1 += __shfl_xor(a1, o);
    }
    if (lane == 0){
        out[n * 2 + 0] = a0 + bm2[0];
        out[n * 2 + 1] = a1 + bm2[1];
    }
}

extern "C" void kernel_launch(void* const* d_in, const int* in_sizes, int n_in,
                              void* d_out, int out_size, void* d_ws, size_t ws_size,
                              hipStream_t stream) {
    const float* feat  = (const float*)d_in[0];
    const int*   src   = (const int*)  d_in[1];
    const int*   dst   = (const int*)  d_in[2];
    const float* W1    = (const float*)d_in[3];
    const float* al1   = (const float*)d_in[4];
    const float* ar1   = (const float*)d_in[5];
    const float* b1    = (const float*)d_in[6];
    const float* W2    = (const float*)d_in[7];
    const float* al2   = (const float*)d_in[8];
    const float* ar2   = (const float*)d_in[9];
    const float* b2    = (const float*)d_in[10];
    const float* Wm1   = (const float*)d_in[11];
    const float* bm1   = (const float*)d_in[12];
    const float* gamma = (const float*)d_in[13];
    const float* beta  = (const float*)d_in[14];
    const float* Wm2   = (const float*)d_in[15];
    const float* bm2   = (const float*)d_in[16];
    const int E = in_sizes[1];
    float* out = (float*)d_out;

    // workspace layout
    float* h_big  = (float*)d_ws;                         // N*256 (h1/h2, then z N*200)
    float* out_l  = h_big + (size_t)NNODES * 256;         // N*64
    float* el     = out_l + (size_t)NNODES * 64;          // N*4
    float* er     = el    + (size_t)NNODES * 4;           // N*4
    float* bn_sum   = er + (size_t)NNODES * 4;            // 200
    float* bn_sumsq = bn_sum + MLP_HID;                   // 200
    float* bn_scale = bn_sumsq + MLP_HID;                 // 200
    float* bn_shift = bn_scale + MLP_HID;                 // 200
    int* cnt      = (int*)(bn_shift + MLP_HID);           // N
    int* row_ptr  = cnt + NNODES;                         // N+1
    int* cursor   = row_ptr + NNODES + 1;                 // N
    int* col_src  = cursor + NNODES;                      // E

    const dim3 blk(256);
    const int eg = (E + 255) / 256;

    // ---- CSR build (once, shared by both layers) ----
    hipMemsetAsync(cnt, 0, NNODES * 4, stream);
    csr_count<<<eg, blk, 0, stream>>>(dst, cnt, E);
    csr_scan<<<1, 1024, 0, stream>>>(cnt, row_ptr, cursor);
    csr_scatter<<<eg, blk, 0, stream>>>(src, dst, cursor, col_src, E);

    auto run_layer = [&](const float* x, int K, const float* W,
                         const float* al, const float* ar, const float* b){
        if (K == 128)
            gemm_tile<128,false><<<dim3(4, (NNODES + 63) / 64), blk, 0, stream>>>(
                x, W, nullptr, h_big, NNODES, 256);
        else
            gemm_tile<64,false><<<dim3(4, (NNODES + 63) / 64), blk, 0, stream>>>(
                x, W, nullptr, h_big, NNODES, 256);
        attn_dots<<<(NNODES * 4 * 64 + 255) / 256, blk, 0, stream>>>(
            h_big, al, ar, el, er, NNODES * 4);
        gat_edge_fused<<<NNODES, blk, 0, stream>>>(
            row_ptr, col_src, el, er, h_big, b, out_l);
    };

    run_layer(feat,  128, W1, al1, ar1, b1);
    run_layer(out_l,  64, W2, al2, ar2, b2);

    // MLP: z = relu(out_l @ Wm1 + bm1)
    gemm_tile<64,true><<<dim3((MLP_HID + 63) / 64, (NNODES + 63) / 64), blk, 0, stream>>>(
        out_l, Wm1, bm1, h_big, NNODES, MLP_HID);

    hipMemsetAsync(bn_sum, 0, 2 * MLP_HID * 4, stream);
    bn_stats<<<(NNODES + 255) / 256, blk, 0, stream>>>(h_big, bn_sum, bn_sumsq, NNODES);
    bn_final<<<1, 256, 0, stream>>>(bn_sum, bn_sumsq, gamma, beta, bn_scale, bn_shift, NNODES);
    mlp2<<<(NNODES * 64 + 255) / 256, blk, 0, stream>>>(
        h_big, bn_scale, bn_shift, Wm2, bm2, out, NNODES);
}

// Round 3
// 743.745 us; speedup vs baseline: 2.4479x; 1.2632x over previous
//
#include <hip/hip_runtime.h>
#include <hip/hip_bf16.h>

#define NNODES 50000
#define MLP_HID 200

__device__ __forceinline__ unsigned short f2bf(float x){
    unsigned u = __float_as_uint(x);
    unsigned r = (u + 0x7fffu + ((u >> 16) & 1u)) >> 16;
    return (unsigned short)r;
}
__device__ __forceinline__ float bf2f(unsigned short b){
    return __uint_as_float(((unsigned)b) << 16);
}

// ---------------- GEMM + attn-dot epilogue: h=x@W -> bf16, el/er fused -------
// Nc fixed = 256; blockIdx.x = head (c0 = head*64)
template<int KT>
__global__ __launch_bounds__(256) void gemm_attn(const float* __restrict__ A,
                                                 const float* __restrict__ B,
                                                 const float* __restrict__ al,
                                                 const float* __restrict__ ar,
                                                 unsigned short* __restrict__ Cbf,
                                                 float* __restrict__ el,
                                                 float* __restrict__ er,
                                                 int M){
    __shared__ float As[16][64];
    __shared__ float Bs[16][64];
    const int tid = threadIdx.x;
    const int tx = tid & 15, ty = tid >> 4;
    const int r0 = blockIdx.y * 64;
    const int h  = blockIdx.x;           // head
    const int c0 = h * 64;
    float acc[4][4] = {};
    const int lr  = tid >> 2,  lk4 = (tid & 3) * 4;   // A-tile load map
    const int bk  = tid >> 4,  bc4 = (tid & 15) * 4;  // B-tile load map

    for (int k0 = 0; k0 < KT; k0 += 16){
        float4 av = make_float4(0.f,0.f,0.f,0.f);
        if (r0 + lr < M) av = *(const float4*)&A[(size_t)(r0 + lr) * KT + k0 + lk4];
        As[lk4+0][lr] = av.x; As[lk4+1][lr] = av.y;
        As[lk4+2][lr] = av.z; As[lk4+3][lr] = av.w;

        float4 bv = *(const float4*)&B[(size_t)(k0 + bk) * 256 + c0 + bc4];
        Bs[bk][bc4+0] = bv.x; Bs[bk][bc4+1] = bv.y;
        Bs[bk][bc4+2] = bv.z; Bs[bk][bc4+3] = bv.w;
        __syncthreads();
        #pragma unroll
        for (int kk = 0; kk < 16; kk++){
            float4 a = *(const float4*)&As[kk][ty*4];
            float4 b = *(const float4*)&Bs[kk][tx*4];
            float arr[4] = {a.x,a.y,a.z,a.w};
            float brr[4] = {b.x,b.y,b.z,b.w};
            #pragma unroll
            for (int i = 0; i < 4; i++)
                #pragma unroll
                for (int j = 0; j < 4; j++)
                    acc[i][j] = fmaf(arr[i], brr[j], acc[i][j]);
        }
        __syncthreads();
    }

    const float al0 = al[h*64 + tx*4 + 0], al1v = al[h*64 + tx*4 + 1];
    const float al2v = al[h*64 + tx*4 + 2], al3 = al[h*64 + tx*4 + 3];
    const float ar0 = ar[h*64 + tx*4 + 0], ar1v = ar[h*64 + tx*4 + 1];
    const float ar2v = ar[h*64 + tx*4 + 2], ar3 = ar[h*64 + tx*4 + 3];

    #pragma unroll
    for (int i = 0; i < 4; i++){
        int r = r0 + ty*4 + i;                 // uniform across the 16-lane tx group
        if (r >= M) continue;
        // bf16 store of h row segment
        ushort4 pk;
        pk.x = f2bf(acc[i][0]); pk.y = f2bf(acc[i][1]);
        pk.z = f2bf(acc[i][2]); pk.w = f2bf(acc[i][3]);
        *(ushort4*)&Cbf[(size_t)r * 256 + h * 64 + tx * 4] = pk;
        // fused attention dots
        float vl = acc[i][0]*al0 + acc[i][1]*al1v + acc[i][2]*al2v + acc[i][3]*al3;
        float vr = acc[i][0]*ar0 + acc[i][1]*ar1v + acc[i][2]*ar2v + acc[i][3]*ar3;
        #pragma unroll
        for (int o = 8; o > 0; o >>= 1){       // reduce across tx (bits 0-3 of tid)
            vl += __shfl_xor(vl, o);
            vr += __shfl_xor(vr, o);
        }
        if (tx == 0){
            el[r * 4 + h] = vl;
            er[r * 4 + h] = vr;
        }
    }
}

// ---------------- plain f32 GEMM (MLP layer): +bias +relu --------------------
template<int KT, bool RELU>
__global__ __launch_bounds__(256) void gemm_tile(const float* __restrict__ A,
                                                 const float* __restrict__ B,
                                                 const float* __restrict__ bias,
                                                 float* __restrict__ C,
                                                 int M, int Nc){
    __shared__ float As[16][64];
    __shared__ float Bs[16][64];
    const int tid = threadIdx.x;
    const int tx = tid & 15, ty = tid >> 4;
    const int r0 = blockIdx.y * 64, c0 = blockIdx.x * 64;
    float acc[4][4] = {};
    const int lr  = tid >> 2,  lk4 = (tid & 3) * 4;
    const int bk  = tid >> 4,  bc4 = (tid & 15) * 4;

    for (int k0 = 0; k0 < KT; k0 += 16){
        float4 av = make_float4(0.f,0.f,0.f,0.f);
        if (r0 + lr < M) av = *(const float4*)&A[(size_t)(r0 + lr) * KT + k0 + lk4];
        As[lk4+0][lr] = av.x; As[lk4+1][lr] = av.y;
        As[lk4+2][lr] = av.z; As[lk4+3][lr] = av.w;

        if (c0 + bc4 + 3 < Nc){
            float4 bv = *(const float4*)&B[(size_t)(k0 + bk) * Nc + c0 + bc4];
            Bs[bk][bc4+0] = bv.x; Bs[bk][bc4+1] = bv.y;
            Bs[bk][bc4+2] = bv.z; Bs[bk][bc4+3] = bv.w;
        } else {
            #pragma unroll
            for (int j = 0; j < 4; j++){
                int c = c0 + bc4 + j;
                Bs[bk][bc4+j] = (c < Nc) ? B[(size_t)(k0 + bk) * Nc + c] : 0.f;
            }
        }
        __syncthreads();
        #pragma unroll
        for (int kk = 0; kk < 16; kk++){
            float4 a = *(const float4*)&As[kk][ty*4];
            float4 b = *(const float4*)&Bs[kk][tx*4];
            float arr[4] = {a.x,a.y,a.z,a.w};
            float brr[4] = {b.x,b.y,b.z,b.w};
            #pragma unroll
            for (int i = 0; i < 4; i++)
                #pragma unroll
                for (int j = 0; j < 4; j++)
                    acc[i][j] = fmaf(arr[i], brr[j], acc[i][j]);
        }
        __syncthreads();
    }
    #pragma unroll
    for (int i = 0; i < 4; i++){
        int r = r0 + ty*4 + i;
        if (r >= M) continue;
        #pragma unroll
        for (int j = 0; j < 4; j++){
            int c = c0 + tx*4 + j;
            if (c >= Nc) continue;
            float v = acc[i][j];
            if (bias) v += bias[c];
            if (RELU) v = fmaxf(v, 0.f);
            C[(size_t)r * Nc + c] = v;
        }
    }
}

// ---------------- CSR build ----------------
__global__ __launch_bounds__(256) void csr_count(const int* __restrict__ dst,
                                                 int* __restrict__ cnt, int E){
    int e = blockIdx.x * blockDim.x + threadIdx.x;
    if (e < E) atomicAdd(&cnt[dst[e]], 1);
}

__global__ __launch_bounds__(1024) void csr_scan(const int* __restrict__ cnt,
                                                 int* __restrict__ row_ptr,
                                                 int* __restrict__ cursor){
    __shared__ int part[1024];
    const int t = threadIdx.x;
    const int CH = (NNODES + 1023) / 1024;
    const int base = t * CH;
    int s = 0;
    for (int i = 0; i < CH; i++){
        int idx = base + i;
        if (idx < NNODES) s += cnt[idx];
    }
    part[t] = s;
    __syncthreads();
    for (int off = 1; off < 1024; off <<= 1){
        int v = (t >= off) ? part[t - off] : 0;
        __syncthreads();
        part[t] += v;
        __syncthreads();
    }
    int run = part[t] - s;
    for (int i = 0; i < CH; i++){
        int idx = base + i;
        if (idx < NNODES){
            row_ptr[idx] = run;
            cursor[idx]  = run;
            run += cnt[idx];
        }
    }
    if (t == 1023) row_ptr[NNODES] = part[1023];
}

__global__ __launch_bounds__(256) void csr_scatter(const int* __restrict__ src,
                                                   const int* __restrict__ dst,
                                                   int* __restrict__ cursor,
                                                   int* __restrict__ col_src, int E){
    int e = blockIdx.x * blockDim.x + threadIdx.x;
    if (e >= E) return;
    int pos = atomicAdd(&cursor[dst[e]], 1);
    col_src[pos] = src[e];
}

// ---------------- fused edge softmax + bf16 gather-agg + epilogue ------------
__global__ __launch_bounds__(256) void gat_edge_fused(
    const int* __restrict__ row_ptr, const int* __restrict__ col_src,
    const float* __restrict__ el, const float* __restrict__ er,
    const unsigned short* __restrict__ hb, const float* __restrict__ b,
    float* __restrict__ out)
{
    const int n    = blockIdx.x;
    const int lane = threadIdx.x & 63;
    const int h    = threadIdx.x >> 6;
    const int rs = row_ptr[n], re = row_ptr[n + 1];
    const int K  = re - rs;
    const float er_h = er[n * 4 + h];

    // phase 1a: max
    float lm = -1e30f;
    for (int k = lane; k < K; k += 64){
        int s = col_src[rs + k];
        float e = el[s * 4 + h] + er_h;
        e = (e >= 0.f) ? e : 0.2f * e;
        lm = fmaxf(lm, e);
    }
    #pragma unroll
    for (int o = 32; o > 0; o >>= 1) lm = fmaxf(lm, __shfl_xor(lm, o));

    // phase 1b: sum of exp
    float ls = 0.f;
    for (int k = lane; k < K; k += 64){
        int s = col_src[rs + k];
        float e = el[s * 4 + h] + er_h;
        e = (e >= 0.f) ? e : 0.2f * e;
        ls += __expf(e - lm);
    }
    #pragma unroll
    for (int o = 32; o > 0; o >>= 1) ls += __shfl_xor(ls, o);
    const float inv_s = 1.f / ls;

    // phase 2: weighted bf16 gather
    float acc0 = 0.f, acc1 = 0.f;
    for (int kc = 0; kc < K; kc += 64){
        int rem = min(64, K - kc);
        float w = 0.f; int sidx = 0;
        if (lane < rem){
            int s = col_src[rs + kc + lane];
            float e = el[s * 4 + h] + er_h;
            e = (e >= 0.f) ? e : 0.2f * e;
            w = __expf(e - lm) * inv_s;
            sidx = s;
        }
        int j = 0;
        for (; j + 1 < rem; j += 2){
            float w0 = __shfl(w, j),     w1 = __shfl(w, j + 1);
            int   s0 = __shfl(sidx, j),  s1 = __shfl(sidx, j + 1);
            float v0 = bf2f(hb[(size_t)s0 * 256 + h * 64 + lane]);
            float v1 = bf2f(hb[(size_t)s1 * 256 + h * 64 + lane]);
            acc0 = fmaf(w0, v0, acc0);
            acc1 = fmaf(w1, v1, acc1);
        }
        if (j < rem){
            float wj = __shfl(w, j);
            int   sj = __shfl(sidx, j);
            acc0 = fmaf(wj, bf2f(hb[(size_t)sj * 256 + h * 64 + lane]), acc0);
        }
    }
    float acc = acc0 + acc1;

    // epilogue: relu(acc + b), mean over heads
    float v = fmaxf(acc + b[h * 64 + lane], 0.f);
    __shared__ float red[4][64];
    red[h][lane] = v;
    __syncthreads();
    if (h == 0){
        out[(size_t)n * 64 + lane] =
            (red[0][lane] + red[1][lane] + red[2][lane] + red[3][lane]) * 0.25f;
    }
}

// ---------------- BN stats ---------------------------------------------------
__global__ __launch_bounds__(256) void bn_stats(const float* __restrict__ z,
                                                float* __restrict__ bsum,
                                                float* __restrict__ bsumsq,
                                                int Nrows){
    int col = threadIdx.x;
    if (col >= MLP_HID) return;
    int r0 = blockIdx.x * 256;
    int r1 = min(r0 + 256, Nrows);
    float s = 0.f, ss = 0.f;
    for (int r = r0; r < r1; r++){
        float v = z[(size_t)r * MLP_HID + col];
        s += v; ss += v * v;
    }
    atomicAdd(&bsum[col], s);
    atomicAdd(&bsumsq[col], ss);
}

__global__ void bn_final(const float* __restrict__ bsum,
                         const float* __restrict__ bsumsq,
                         const float* __restrict__ gamma,
                         const float* __restrict__ beta,
                         float* __restrict__ scale,
                         float* __restrict__ shift,
                         int Nrows){
    int col = threadIdx.x;
    if (col >= MLP_HID) return;
    float inv = 1.f / (float)Nrows;
    float mu = bsum[col] * inv;
    float var = bsumsq[col] * inv - mu * mu;
    float rstd = rsqrtf(var + 1e-5f);
    float sc = rstd * gamma[col];
    scale[col] = sc;
    shift[col] = beta[col] - mu * sc;
}

// ---------------- final linear ----------------------------------------------
__global__ __launch_bounds__(256) void mlp2(const float* __restrict__ z,
                                            const float* __restrict__ scale,
                                            const float* __restrict__ shift,
                                            const float* __restrict__ Wm2,
                                            const float* __restrict__ bm2,
                                            float* __restrict__ out,
                                            int Nrows){
    int g = blockIdx.x * blockDim.x + threadIdx.x;
    int n = g >> 6;
    if (n >= Nrows) return;
    int lane = threadIdx.x & 63;
    float a0 = 0.f, a1 = 0.f;
    for (int k = lane; k < MLP_HID; k += 64){
        float zn = z[(size_t)n * MLP_HID + k] * scale[k] + shift[k];
        a0 = fmaf(zn, Wm2[k * 2 + 0], a0);
        a1 = fmaf(zn, Wm2[k * 2 + 1], a1);
    }
    #pragma unroll
    for (int o = 32; o > 0; o >>= 1){
        a0 += __shfl_xor(a0, o);
        a1 += __shfl_xor(a1, o);
    }
    if (lane == 0){
        out[n * 2 + 0] = a0 + bm2[0];
        out[n * 2 + 1] = a1 + bm2[1];
    }
}

extern "C" void kernel_launch(void* const* d_in, const int* in_sizes, int n_in,
                              void* d_out, int out_size, void* d_ws, size_t ws_size,
                              hipStream_t stream) {
    const float* feat  = (const float*)d_in[0];
    const int*   src   = (const int*)  d_in[1];
    const int*   dst   = (const int*)  d_in[2];
    const float* W1    = (const float*)d_in[3];
    const float* al1   = (const float*)d_in[4];
    const float* ar1   = (const float*)d_in[5];
    const float* b1    = (const float*)d_in[6];
    const float* W2    = (const float*)d_in[7];
    const float* al2   = (const float*)d_in[8];
    const float* ar2   = (const float*)d_in[9];
    const float* b2    = (const float*)d_in[10];
    const float* Wm1   = (const float*)d_in[11];
    const float* bm1   = (const float*)d_in[12];
    const float* gamma = (const float*)d_in[13];
    const float* beta  = (const float*)d_in[14];
    const float* Wm2   = (const float*)d_in[15];
    const float* bm2   = (const float*)d_in[16];
    const int E = in_sizes[1];
    float* out = (float*)d_out;

    // workspace layout
    unsigned short* h_bf = (unsigned short*)d_ws;             // N*256 bf16
    float* out_l  = (float*)(h_bf + (size_t)NNODES * 256);    // N*64
    float* z      = out_l + (size_t)NNODES * 64;              // N*200
    float* el     = z     + (size_t)NNODES * MLP_HID;         // N*4
    float* er     = el    + (size_t)NNODES * 4;               // N*4
    float* bn_sum   = er + (size_t)NNODES * 4;                // 200
    float* bn_sumsq = bn_sum + MLP_HID;                       // 200
    float* bn_scale = bn_sumsq + MLP_HID;                     // 200
    float* bn_shift = bn_scale + MLP_HID;                     // 200
    int* cnt      = (int*)(bn_shift + MLP_HID);               // N
    int* row_ptr  = cnt + NNODES;                             // N+1
    int* cursor   = row_ptr + NNODES + 1;                     // N
    int* col_src  = cursor + NNODES;                          // E

    const dim3 blk(256);
    const int eg = (E + 255) / 256;
    const int rb = (NNODES + 63) / 64;

    // ---- CSR build (once, shared by both layers) ----
    hipMemsetAsync(cnt, 0, NNODES * 4, stream);
    csr_count<<<eg, blk, 0, stream>>>(dst, cnt, E);
    csr_scan<<<1, 1024, 0, stream>>>(cnt, row_ptr, cursor);
    csr_scatter<<<eg, blk, 0, stream>>>(src, dst, cursor, col_src, E);

    // ---- layer 1 ----
    gemm_attn<128><<<dim3(4, rb), blk, 0, stream>>>(feat, W1, al1, ar1, h_bf, el, er, NNODES);
    gat_edge_fused<<<NNODES, blk, 0, stream>>>(row_ptr, col_src, el, er, h_bf, b1, out_l);

    // ---- layer 2 ----
    gemm_attn<64><<<dim3(4, rb), blk, 0, stream>>>(out_l, W2, al2, ar2, h_bf, el, er, NNODES);
    gat_edge_fused<<<NNODES, blk, 0, stream>>>(row_ptr, col_src, el, er, h_bf, b2, out_l);

    // ---- MLP ----
    gemm_tile<64,true><<<dim3((MLP_HID + 63) / 64, rb), blk, 0, stream>>>(
        out_l, Wm1, bm1, z, NNODES, MLP_HID);

    hipMemsetAsync(bn_sum, 0, 2 * MLP_HID * 4, stream);
    bn_stats<<<(NNODES + 255) / 256, blk, 0, stream>>>(z, bn_sum, bn_sumsq, NNODES);
    bn_final<<<1, 256, 0, stream>>>(bn_sum, bn_sumsq, gamma, beta, bn_scale, bn_shift, NNODES);
    mlp2<<<(NNODES * 64 + 255) / 256, blk, 0, stream>>>(
        z, bn_scale, bn_shift, Wm2, bm2, out, NNODES);
}

// Round 4
// 649.000 us; speedup vs baseline: 2.8052x; 1.1460x over previous
//
#include <hip/hip_runtime.h>
#include <hip/hip_bf16.h>

#define NNODES 50000
#define MLP_HID 200

typedef __attribute__((ext_vector_type(8))) short bf16x8;
typedef __attribute__((ext_vector_type(4))) float f32x4;

__device__ __forceinline__ unsigned short f2bf(float x){
    unsigned u = __float_as_uint(x);
    unsigned r = (u + 0x7fffu + ((u >> 16) & 1u)) >> 16;
    return (unsigned short)r;
}
__device__ __forceinline__ float bflo(unsigned u){ return __uint_as_float(u << 16); }
__device__ __forceinline__ float bfhi(unsigned u){ return __uint_as_float(u & 0xffff0000u); }

// ---------------- converts ----------------
__global__ __launch_bounds__(256) void conv_bf(const float* __restrict__ X,
                                               unsigned short* __restrict__ Y,
                                               long n){
    long i = ((long)blockIdx.x * 256 + threadIdx.x) * 4;
    if (i >= n) return;
    float4 v = *(const float4*)&X[i];
    ushort4 p;
    p.x = f2bf(v.x); p.y = f2bf(v.y); p.z = f2bf(v.z); p.w = f2bf(v.w);
    *(ushort4*)&Y[i] = p;
}

// W[K][256] -> WT[256][K] bf16
__global__ __launch_bounds__(256) void conv_wt(const float* __restrict__ W,
                                               unsigned short* __restrict__ WT,
                                               int K){
    int c = blockIdx.x;
    for (int k = threadIdx.x; k < K; k += 256)
        WT[(size_t)c * K + k] = f2bf(W[(size_t)k * 256 + c]);
}

// ---------------- MFMA GEMM + attn-dot epilogue ------------------------------
// h[M x 256] = A[M x K] @ W[K x 256]; WT is [256][K]. One wave -> 16 rows x 256 cols.
template<int K>
__global__ __launch_bounds__(256) void mfma_gemm_attn(
    const unsigned short* __restrict__ Abf,
    const unsigned short* __restrict__ WT,
    const float* __restrict__ al, const float* __restrict__ ar,
    unsigned short* __restrict__ hb,
    float* __restrict__ el, float* __restrict__ er, int M)
{
    const int wv = threadIdx.x >> 6, lane = threadIdx.x & 63;
    const int r0 = blockIdx.x * 64 + wv * 16;
    const int l15 = lane & 15, ks = lane >> 4;

    f32x4 acc[16];
    #pragma unroll
    for (int nt = 0; nt < 16; nt++)
        #pragma unroll
        for (int q = 0; q < 4; q++) acc[nt][q] = 0.f;

    const int arow = min(r0 + l15, M - 1);
    const unsigned short* aptr = Abf + (size_t)arow * K + ks * 8;
    const unsigned short* bptr = WT + (size_t)l15 * K + ks * 8;

    #pragma unroll
    for (int k0 = 0; k0 < K; k0 += 32){
        bf16x8 a = *(const bf16x8*)(aptr + k0);
        #pragma unroll
        for (int nt = 0; nt < 16; nt++){
            bf16x8 b = *(const bf16x8*)(bptr + (size_t)nt * 16 * K + k0);
            acc[nt] = __builtin_amdgcn_mfma_f32_16x16x32_bf16(a, b, acc[nt], 0, 0, 0);
        }
    }

    // ---- el/er epilogue: value (nt,reg) = h[row=ks*4+reg][col=nt*16+l15] ----
    float elv[4][4], erv[4][4];
    #pragma unroll
    for (int r = 0; r < 4; r++)
        #pragma unroll
        for (int hh = 0; hh < 4; hh++){ elv[r][hh] = 0.f; erv[r][hh] = 0.f; }

    #pragma unroll
    for (int nt = 0; nt < 16; nt++){
        int col = nt * 16 + l15;
        float alv = al[col], arv = ar[col];
        #pragma unroll
        for (int reg = 0; reg < 4; reg++){
            elv[reg][nt >> 2] = fmaf(acc[nt][reg], alv, elv[reg][nt >> 2]);
            erv[reg][nt >> 2] = fmaf(acc[nt][reg], arv, erv[reg][nt >> 2]);
        }
    }
    #pragma unroll
    for (int o = 8; o > 0; o >>= 1){
        #pragma unroll
        for (int reg = 0; reg < 4; reg++)
            #pragma unroll
            for (int hh = 0; hh < 4; hh++){
                elv[reg][hh] += __shfl_xor(elv[reg][hh], o);
                erv[reg][hh] += __shfl_xor(erv[reg][hh], o);
            }
    }
    if (l15 == 0){
        #pragma unroll
        for (int reg = 0; reg < 4; reg++){
            int r = r0 + ks * 4 + reg;
            if (r < M){
                #pragma unroll
                for (int hh = 0; hh < 4; hh++){
                    el[r * 4 + hh] = elv[reg][hh];
                    er[r * 4 + hh] = erv[reg][hh];
                }
            }
        }
    }

    // ---- bf16 h store via per-wave LDS repack ----
    __shared__ __align__(16) unsigned short hbuf[4][16][264];
    #pragma unroll
    for (int nt = 0; nt < 16; nt++)
        #pragma unroll
        for (int reg = 0; reg < 4; reg++)
            hbuf[wv][ks * 4 + reg][nt * 16 + l15] = f2bf(acc[nt][reg]);
    // wave-local dependence: compiler inserts lgkmcnt waits
    #pragma unroll
    for (int t = 0; t < 8; t++){
        int chunk = t * 64 + lane;       // 0..511
        int rr = chunk >> 5;             // 0..15
        int cc = (chunk & 31) * 8;       // 0..248
        int r = r0 + rr;
        if (r < M){
            uint4 v = *(const uint4*)&hbuf[wv][rr][cc];
            *(uint4*)&hb[(size_t)r * 256 + cc] = v;
        }
    }
}

// ---------------- plain f32 GEMM (MLP layer): +bias +relu --------------------
template<int KT, bool RELU>
__global__ __launch_bounds__(256) void gemm_tile(const float* __restrict__ A,
                                                 const float* __restrict__ B,
                                                 const float* __restrict__ bias,
                                                 float* __restrict__ C,
                                                 int M, int Nc){
    __shared__ float As[16][64];
    __shared__ float Bs[16][64];
    const int tid = threadIdx.x;
    const int tx = tid & 15, ty = tid >> 4;
    const int r0 = blockIdx.y * 64, c0 = blockIdx.x * 64;
    float acc[4][4] = {};
    const int lr  = tid >> 2,  lk4 = (tid & 3) * 4;
    const int bk  = tid >> 4,  bc4 = (tid & 15) * 4;

    for (int k0 = 0; k0 < KT; k0 += 16){
        float4 av = make_float4(0.f,0.f,0.f,0.f);
        if (r0 + lr < M) av = *(const float4*)&A[(size_t)(r0 + lr) * KT + k0 + lk4];
        As[lk4+0][lr] = av.x; As[lk4+1][lr] = av.y;
        As[lk4+2][lr] = av.z; As[lk4+3][lr] = av.w;

        if (c0 + bc4 + 3 < Nc){
            float4 bv = *(const float4*)&B[(size_t)(k0 + bk) * Nc + c0 + bc4];
            Bs[bk][bc4+0] = bv.x; Bs[bk][bc4+1] = bv.y;
            Bs[bk][bc4+2] = bv.z; Bs[bk][bc4+3] = bv.w;
        } else {
            #pragma unroll
            for (int j = 0; j < 4; j++){
                int c = c0 + bc4 + j;
                Bs[bk][bc4+j] = (c < Nc) ? B[(size_t)(k0 + bk) * Nc + c] : 0.f;
            }
        }
        __syncthreads();
        #pragma unroll
        for (int kk = 0; kk < 16; kk++){
            float4 a = *(const float4*)&As[kk][ty*4];
            float4 b = *(const float4*)&Bs[kk][tx*4];
            float arr[4] = {a.x,a.y,a.z,a.w};
            float brr[4] = {b.x,b.y,b.z,b.w};
            #pragma unroll
            for (int i = 0; i < 4; i++)
                #pragma unroll
                for (int j = 0; j < 4; j++)
                    acc[i][j] = fmaf(arr[i], brr[j], acc[i][j]);
        }
        __syncthreads();
    }
    #pragma unroll
    for (int i = 0; i < 4; i++){
        int r = r0 + ty*4 + i;
        if (r >= M) continue;
        #pragma unroll
        for (int j = 0; j < 4; j++){
            int c = c0 + tx*4 + j;
            if (c >= Nc) continue;
            float v = acc[i][j];
            if (bias) v += bias[c];
            if (RELU) v = fmaxf(v, 0.f);
            C[(size_t)r * Nc + c] = v;
        }
    }
}

// ---------------- CSR build ----------------
__global__ __launch_bounds__(256) void csr_count(const int* __restrict__ dst,
                                                 int* __restrict__ cnt, int E){
    int e = blockIdx.x * blockDim.x + threadIdx.x;
    if (e < E) atomicAdd(&cnt[dst[e]], 1);
}

__global__ __launch_bounds__(1024) void csr_scan(const int* __restrict__ cnt,
                                                 int* __restrict__ row_ptr,
                                                 int* __restrict__ cursor){
    __shared__ int part[1024];
    const int t = threadIdx.x;
    const int CH = (NNODES + 1023) / 1024;
    const int base = t * CH;
    int s = 0;
    for (int i = 0; i < CH; i++){
        int idx = base + i;
        if (idx < NNODES) s += cnt[idx];
    }
    part[t] = s;
    __syncthreads();
    for (int off = 1; off < 1024; off <<= 1){
        int v = (t >= off) ? part[t - off] : 0;
        __syncthreads();
        part[t] += v;
        __syncthreads();
    }
    int run = part[t] - s;
    for (int i = 0; i < CH; i++){
        int idx = base + i;
        if (idx < NNODES){
            row_ptr[idx] = run;
            cursor[idx]  = run;
            run += cnt[idx];
        }
    }
    if (t == 1023) row_ptr[NNODES] = part[1023];
}

__global__ __launch_bounds__(256) void csr_scatter(const int* __restrict__ src,
                                                   const int* __restrict__ dst,
                                                   int* __restrict__ cursor,
                                                   int* __restrict__ col_src, int E){
    int e = blockIdx.x * blockDim.x + threadIdx.x;
    if (e >= E) return;
    int pos = atomicAdd(&cursor[dst[e]], 1);
    col_src[pos] = src[e];
}

// ---------------- fused edge softmax + wide gather + epilogue ----------------
// one block per dst node. Phase 1: per-head wave softmax stats.
// Phase 2: 8 edge-slots x 32 threads x 8 dims, 16B loads, weights via LDS.
__global__ __launch_bounds__(256) void gat_edge_v2(
    const int* __restrict__ row_ptr, const int* __restrict__ col_src,
    const float* __restrict__ el, const float* __restrict__ er,
    const unsigned short* __restrict__ hb, const float* __restrict__ bias,
    float* __restrict__ out_f, unsigned short* __restrict__ out_b)
{
    __shared__ float s_lm[4], s_inv[4], s_er[4];
    __shared__ int   s_idx[64];
    __shared__ float s_w[64][4];
    __shared__ __align__(16) float s_red[8][264];
    __shared__ float s_val[256];

    const int n = blockIdx.x;
    const int tid = threadIdx.x;
    const int lane = tid & 63;
    const int h = tid >> 6;
    const int rs = row_ptr[n], re = row_ptr[n + 1];
    const int K = re - rs;

    // phase 1 (wave h = head h)
    const float er_h = er[n * 4 + h];
    float lm = -1e30f;
    for (int k = lane; k < K; k += 64){
        int s = col_src[rs + k];
        float e = el[s * 4 + h] + er_h;
        e = (e >= 0.f) ? e : 0.2f * e;
        lm = fmaxf(lm, e);
    }
    #pragma unroll
    for (int o = 32; o > 0; o >>= 1) lm = fmaxf(lm, __shfl_xor(lm, o));
    float ls = 0.f;
    for (int k = lane; k < K; k += 64){
        int s = col_src[rs + k];
        float e = el[s * 4 + h] + er_h;
        e = (e >= 0.f) ? e : 0.2f * e;
        ls += __expf(e - lm);
    }
    #pragma unroll
    for (int o = 32; o > 0; o >>= 1) ls += __shfl_xor(ls, o);
    if (lane == 0){ s_lm[h] = lm; s_inv[h] = 1.f / ls; s_er[h] = er_h; }
    __syncthreads();

    // phase 2: chunked wide gather
    float acc[8];
    #pragma unroll
    for (int q = 0; q < 8; q++) acc[q] = 0.f;
    const int slot = tid >> 5;            // 0..7 edge slot
    const int c8   = (tid & 31) * 8;      // dim chunk
    const int hc   = c8 >> 6;             // head of this chunk
    const int kl   = tid >> 2, hw = tid & 3;

    for (int kc = 0; kc < K; kc += 64){
        int rem = min(64, K - kc);
        if (kc) __syncthreads();          // protect LDS reuse
        if (kl < rem){
            int s = col_src[rs + kc + kl];
            float e = el[s * 4 + hw] + s_er[hw];
            e = (e >= 0.f) ? e : 0.2f * e;
            s_w[kl][hw] = __expf(e - s_lm[hw]) * s_inv[hw];
            if (hw == 0) s_idx[kl] = s;
        }
        __syncthreads();
        for (int j = slot; j < rem; j += 8){
            int s = s_idx[j];
            float w = s_w[j][hc];
            uint4 pv = *(const uint4*)&hb[(size_t)s * 256 + c8];
            acc[0] = fmaf(w, bflo(pv.x), acc[0]);
            acc[1] = fmaf(w, bfhi(pv.x), acc[1]);
            acc[2] = fmaf(w, bflo(pv.y), acc[2]);
            acc[3] = fmaf(w, bfhi(pv.y), acc[3]);
            acc[4] = fmaf(w, bflo(pv.z), acc[4]);
            acc[5] = fmaf(w, bfhi(pv.z), acc[5]);
            acc[6] = fmaf(w, bflo(pv.w), acc[6]);
            acc[7] = fmaf(w, bfhi(pv.w), acc[7]);
        }
    }

    // reduce across 8 slots
    *(float4*)&s_red[slot][c8]     = make_float4(acc[0], acc[1], acc[2], acc[3]);
    *(float4*)&s_red[slot][c8 + 4] = make_float4(acc[4], acc[5], acc[6], acc[7]);
    __syncthreads();
    {
        int d = tid;                      // 0..255 output dim
        float v = 0.f;
        #pragma unroll
        for (int j = 0; j < 8; j++) v += s_red[j][d];
        v = fmaxf(v + bias[d], 0.f);
        s_val[d] = v;
    }
    __syncthreads();
    if (tid < 64){
        float m = (s_val[tid] + s_val[tid + 64] + s_val[tid + 128] + s_val[tid + 192]) * 0.25f;
        out_f[(size_t)n * 64 + tid] = m;
        out_b[(size_t)n * 64 + tid] = f2bf(m);
    }
}

// ---------------- BN stats ---------------------------------------------------
__global__ __launch_bounds__(256) void bn_stats(const float* __restrict__ z,
                                                float* __restrict__ bsum,
                                                float* __restrict__ bsumsq,
                                                int Nrows){
    int col = threadIdx.x;
    if (col >= MLP_HID) return;
    int r0 = blockIdx.x * 256;
    int r1 = min(r0 + 256, Nrows);
    float s = 0.f, ss = 0.f;
    for (int r = r0; r < r1; r++){
        float v = z[(size_t)r * MLP_HID + col];
        s += v; ss += v * v;
    }
    atomicAdd(&bsum[col], s);
    atomicAdd(&bsumsq[col], ss);
}

__global__ void bn_final(const float* __restrict__ bsum,
                         const float* __restrict__ bsumsq,
                         const float* __restrict__ gamma,
                         const float* __restrict__ beta,
                         float* __restrict__ scale,
                         float* __restrict__ shift,
                         int Nrows){
    int col = threadIdx.x;
    if (col >= MLP_HID) return;
    float inv = 1.f / (float)Nrows;
    float mu = bsum[col] * inv;
    float var = bsumsq[col] * inv - mu * mu;
    float rstd = rsqrtf(var + 1e-5f);
    float sc = rstd * gamma[col];
    scale[col] = sc;
    shift[col] = beta[col] - mu * sc;
}

// ---------------- final linear ----------------------------------------------
__global__ __launch_bounds__(256) void mlp2(const float* __restrict__ z,
                                            const float* __restrict__ scale,
                                            const float* __restrict__ shift,
                                            const float* __restrict__ Wm2,
                                            const float* __restrict__ bm2,
                                            float* __restrict__ out,
                                            int Nrows){
    int g = blockIdx.x * blockDim.x + threadIdx.x;
    int n = g >> 6;
    if (n >= Nrows) return;
    int lane = threadIdx.x & 63;
    float a0 = 0.f, a1 = 0.f;
    for (int k = lane; k < MLP_HID; k += 64){
        float zn = z[(size_t)n * MLP_HID + k] * scale[k] + shift[k];
        a0 = fmaf(zn, Wm2[k * 2 + 0], a0);
        a1 = fmaf(zn, Wm2[k * 2 + 1], a1);
    }
    #pragma unroll
    for (int o = 32; o > 0; o >>= 1){
        a0 += __shfl_xor(a0, o);
        a1 += __shfl_xor(a1, o);
    }
    if (lane == 0){
        out[n * 2 + 0] = a0 + bm2[0];
        out[n * 2 + 1] = a1 + bm2[1];
    }
}

extern "C" void kernel_launch(void* const* d_in, const int* in_sizes, int n_in,
                              void* d_out, int out_size, void* d_ws, size_t ws_size,
                              hipStream_t stream) {
    const float* feat  = (const float*)d_in[0];
    const int*   src   = (const int*)  d_in[1];
    const int*   dst   = (const int*)  d_in[2];
    const float* W1    = (const float*)d_in[3];
    const float* al1   = (const float*)d_in[4];
    const float* ar1   = (const float*)d_in[5];
    const float* b1    = (const float*)d_in[6];
    const float* W2    = (const float*)d_in[7];
    const float* al2   = (const float*)d_in[8];
    const float* ar2   = (const float*)d_in[9];
    const float* b2    = (const float*)d_in[10];
    const float* Wm1   = (const float*)d_in[11];
    const float* bm1   = (const float*)d_in[12];
    const float* gamma = (const float*)d_in[13];
    const float* beta  = (const float*)d_in[14];
    const float* Wm2   = (const float*)d_in[15];
    const float* bm2   = (const float*)d_in[16];
    const int E = in_sizes[1];
    float* out = (float*)d_out;

    // ---- workspace layout ----
    unsigned short* h_bf   = (unsigned short*)d_ws;                 // N*256 bf16
    unsigned short* featbf = h_bf   + (size_t)NNODES * 256;         // N*128 bf16
    unsigned short* o1_bf  = featbf + (size_t)NNODES * 128;         // N*64 bf16
    unsigned short* o2_bf  = o1_bf  + (size_t)NNODES * 64;          // N*64 bf16
    unsigned short* W1T    = o2_bf  + (size_t)NNODES * 64;          // 256*128
    unsigned short* W2T    = W1T + 256 * 128;                       // 256*64
    float* out2_f = (float*)(W2T + 256 * 64);                       // N*64 f32
    float* z      = out2_f + (size_t)NNODES * 64;                   // N*200 f32
    float* el     = z      + (size_t)NNODES * MLP_HID;              // N*4
    float* er     = el     + (size_t)NNODES * 4;                    // N*4
    float* bn_sum   = er + (size_t)NNODES * 4;                      // 200
    float* bn_sumsq = bn_sum + MLP_HID;                             // 200
    float* bn_scale = bn_sumsq + MLP_HID;                           // 200
    float* bn_shift = bn_scale + MLP_HID;                           // 200
    int* cnt      = (int*)(bn_shift + MLP_HID);                     // N
    int* row_ptr  = cnt + NNODES;                                   // N+1
    int* cursor   = row_ptr + NNODES + 1;                           // N
    int* col_src  = cursor + NNODES;                                // E

    const dim3 blk(256);
    const int eg = (E + 255) / 256;
    const int gb = (NNODES + 63) / 64;     // 782 blocks for MFMA gemm
    const int rb = (NNODES + 63) / 64;

    // ---- conversions ----
    conv_bf<<<(int)(((long)NNODES * 128 / 4 + 255) / 256), blk, 0, stream>>>(
        feat, featbf, (long)NNODES * 128);
    conv_wt<<<256, blk, 0, stream>>>(W1, W1T, 128);
    conv_wt<<<256, blk, 0, stream>>>(W2, W2T, 64);

    // ---- CSR build ----
    hipMemsetAsync(cnt, 0, NNODES * 4, stream);
    csr_count<<<eg, blk, 0, stream>>>(dst, cnt, E);
    csr_scan<<<1, 1024, 0, stream>>>(cnt, row_ptr, cursor);
    csr_scatter<<<eg, blk, 0, stream>>>(src, dst, cursor, col_src, E);

    // ---- layer 1 ----
    mfma_gemm_attn<128><<<gb, blk, 0, stream>>>(featbf, W1T, al1, ar1, h_bf, el, er, NNODES);
    gat_edge_v2<<<NNODES, blk, 0, stream>>>(row_ptr, col_src, el, er, h_bf, b1,
                                            z /*scratch f32*/, o1_bf);

    // ---- layer 2 ----
    mfma_gemm_attn<64><<<gb, blk, 0, stream>>>(o1_bf, W2T, al2, ar2, h_bf, el, er, NNODES);
    gat_edge_v2<<<NNODES, blk, 0, stream>>>(row_ptr, col_src, el, er, h_bf, b2,
                                            out2_f, o2_bf);

    // ---- MLP ----
    gemm_tile<64,true><<<dim3((MLP_HID + 63) / 64, rb), blk, 0, stream>>>(
        out2_f, Wm1, bm1, z, NNODES, MLP_HID);

    hipMemsetAsync(bn_sum, 0, 2 * MLP_HID * 4, stream);
    bn_stats<<<(NNODES + 255) / 256, blk, 0, stream>>>(z, bn_sum, bn_sumsq, NNODES);
    bn_final<<<1, 256, 0, stream>>>(bn_sum, bn_sumsq, gamma, beta, bn_scale, bn_shift, NNODES);
    mlp2<<<(NNODES * 64 + 255) / 256, blk, 0, stream>>>(
        z, bn_scale, bn_shift, Wm2, bm2, out, NNODES);
}